// Round 4
// baseline (144.628 us; speedup 1.0000x reference)
//
#include <hip/hip_runtime.h>
#include <math.h>

#define NROWS 16384
#define NCOLS 4096
#define RPC   32          // rows per chunk (NROWS = 512 * 32 exactly)
#define NCHUNK (NROWS / RPC)   // 512 blocks

// ---------------------------------------------------------------------------
// Stage 1: per-(row-chunk) partial sums of the 5 stats for ALL columns.
// One 1024-thread block spans the full 4096-col row (thread t owns cols
// 4t..4t+3, float4). Register double-buffer: issue the next 2 rows' 4 loads
// (p,t) BEFORE accumulating the current 2 rows, so every wave keeps >=4 KB
// of independent loads in flight (round-3 code register-minimized to ~2).
// VGPR target <=64 so 2 blocks/CU stay resident (launch_bounds(1024,8)).
// partial layout: [gy][5][NCOLS] floats.
// ---------------------------------------------------------------------------
#define ACC(P, T)                                                      \
    do {                                                               \
        sp.x  += (P).x;         sp.y  += (P).y;                        \
        sp.z  += (P).z;         sp.w  += (P).w;                        \
        st.x  += (T).x;         st.y  += (T).y;                        \
        st.z  += (T).z;         st.w  += (T).w;                        \
        spp.x += (P).x * (P).x; spp.y += (P).y * (P).y;                \
        spp.z += (P).z * (P).z; spp.w += (P).w * (P).w;                \
        stt.x += (T).x * (T).x; stt.y += (T).y * (T).y;                \
        stt.z += (T).z * (T).z; stt.w += (T).w * (T).w;                \
        spt.x += (P).x * (T).x; spt.y += (P).y * (T).y;                \
        spt.z += (P).z * (T).z; spt.w += (P).w * (T).w;                \
    } while (0)

__global__ __launch_bounds__(1024, 8) void stats_partial_kernel(
    const float* __restrict__ preds,
    const float* __restrict__ targets,
    float* __restrict__ partial)
{
    const int col = threadIdx.x * 4;
    const size_t r0 = (size_t)blockIdx.x * RPC;

    const float* __restrict__ pp = preds   + r0 * NCOLS + col;
    const float* __restrict__ tp = targets + r0 * NCOLS + col;

    float4 sp  = {0.f, 0.f, 0.f, 0.f};
    float4 st  = {0.f, 0.f, 0.f, 0.f};
    float4 spp = {0.f, 0.f, 0.f, 0.f};
    float4 stt = {0.f, 0.f, 0.f, 0.f};
    float4 spt = {0.f, 0.f, 0.f, 0.f};

    // prologue: batch 0 (rows 0,1 of the chunk)
    float4 Pa = *(const float4*)(pp);
    float4 Ta = *(const float4*)(tp);
    float4 Pb = *(const float4*)(pp + NCOLS);
    float4 Tb = *(const float4*)(tp + NCOLS);
    pp += 2 * NCOLS;
    tp += 2 * NCOLS;

    #pragma unroll 2
    for (int r = 0; r < RPC - 2; r += 2) {
        // issue next batch's 4 independent loads first
        float4 Pc = *(const float4*)(pp);
        float4 Tc = *(const float4*)(tp);
        float4 Pd = *(const float4*)(pp + NCOLS);
        float4 Td = *(const float4*)(tp + NCOLS);
        pp += 2 * NCOLS;
        tp += 2 * NCOLS;

        // accumulate current batch while next batch is in flight
        ACC(Pa, Ta);
        ACC(Pb, Tb);

        Pa = Pc; Ta = Tc; Pb = Pd; Tb = Td;
    }
    ACC(Pa, Ta);
    ACC(Pb, Tb);

    float* base = partial + ((size_t)blockIdx.x * 5) * NCOLS + col;
    *(float4*)(base + 0 * NCOLS) = sp;
    *(float4*)(base + 1 * NCOLS) = st;
    *(float4*)(base + 2 * NCOLS) = spp;
    *(float4*)(base + 3 * NCOLS) = stt;
    *(float4*)(base + 4 * NCOLS) = spt;
}

// ---------------------------------------------------------------------------
// Stage 2: reduce partials over chunks + per-column pcc/cos + per-block sum.
// grid = NCOLS/16 = 256 blocks, 256 threads = 16 cols x 16 chunk-lanes.
// Deterministic: fixed loop order, fixed LDS tree, no atomics.
// ---------------------------------------------------------------------------
__global__ __launch_bounds__(256) void reduce_cols_kernel(
    const float* __restrict__ partial,
    float* __restrict__ blocksum)
{
    const int ci  = threadIdx.x & 15;   // column within block
    const int gi  = threadIdx.x >> 4;   // chunk-lane 0..15
    const int col = blockIdx.x * 16 + ci;

    float s[5] = {0.f, 0.f, 0.f, 0.f, 0.f};
    for (int gy = gi; gy < NCHUNK; gy += 16) {
        const float* base = partial + ((size_t)gy * 5) * NCOLS + col;
        #pragma unroll
        for (int k = 0; k < 5; ++k) s[k] += base[k * NCOLS];
    }

    __shared__ float red[256][5];
    #pragma unroll
    for (int k = 0; k < 5; ++k) red[threadIdx.x][k] = s[k];
    __syncthreads();

    __shared__ float colval[16];
    if (threadIdx.x < 16) {
        float t[5] = {0.f, 0.f, 0.f, 0.f, 0.f};
        for (int g = 0; g < 16; ++g) {
            #pragma unroll
            for (int k = 0; k < 5; ++k) t[k] += red[threadIdx.x + 16 * g][k];
        }
        // t = {sum_p, sum_t, sum_pp, sum_tt, sum_pt}
        const float invN = 1.0f / (float)NROWS;
        float mu_p = t[0] * invN;
        float mu_t = t[1] * invN;
        float var_p = fmaxf(t[2] * invN - mu_p * mu_p, 0.f);
        float var_t = fmaxf(t[3] * invN - mu_t * mu_t, 0.f);
        float cov   = t[4] * invN - mu_p * mu_t;

        float denom = sqrtf(var_p * var_t);
        float pcc = (denom > 0.f) ? (cov / denom) : 0.f;  // NaN -> 0 semantics

        float np_ = fmaxf(sqrtf(t[2]), 1e-8f);
        float nt_ = fmaxf(sqrtf(t[3]), 1e-8f);
        float cs  = t[4] / (np_ * nt_);

        colval[threadIdx.x] = pcc + cs;
    }
    __syncthreads();

    if (threadIdx.x == 0) {
        float b = 0.f;
        #pragma unroll
        for (int i = 0; i < 16; ++i) b += colval[i];
        blocksum[blockIdx.x] = b;
    }
}

// ---------------------------------------------------------------------------
// Stage 3: single block folds the 256 block sums into the scalar output.
// out = 2 - (sum of all per-column (pcc+cos)) / NCOLS
// ---------------------------------------------------------------------------
__global__ __launch_bounds__(256) void final_reduce_kernel(
    const float* __restrict__ blocksum,
    float* __restrict__ out)
{
    float v = blocksum[threadIdx.x];
    for (int off = 32; off > 0; off >>= 1)
        v += __shfl_down(v, off, 64);

    __shared__ float w[4];
    const int lane = threadIdx.x & 63;
    const int wid  = threadIdx.x >> 6;
    if (lane == 0) w[wid] = v;
    __syncthreads();

    if (threadIdx.x == 0)
        out[0] = 2.0f - (w[0] + w[1] + w[2] + w[3]) / (float)NCOLS;
}

extern "C" void kernel_launch(void* const* d_in, const int* in_sizes, int n_in,
                              void* d_out, int out_size, void* d_ws, size_t ws_size,
                              hipStream_t stream) {
    const float* preds   = (const float*)d_in[0];
    const float* targets = (const float*)d_in[1];
    float* out = (float*)d_out;
    float* partial = (float*)d_ws;
    // workspace: NCHUNK*5*NCOLS*4 = 40 MB partials + 1 KB blocksums
    // (round 2 observed ws_size ~1 GB, so this fits).
    float* blocksum = partial + (size_t)NCHUNK * 5 * NCOLS;

    stats_partial_kernel<<<NCHUNK, 1024, 0, stream>>>(preds, targets, partial);
    reduce_cols_kernel<<<NCOLS / 16, 256, 0, stream>>>(partial, blocksum);
    final_reduce_kernel<<<1, 256, 0, stream>>>(blocksum, out);
}

// Round 5
// 118.737 us; speedup vs baseline: 1.2181x; 1.2181x over previous
//
#include <hip/hip_runtime.h>
#include <math.h>

#define NROWS 16384
#define NCOLS 4096
#define RPC   64               // rows per chunk
#define NCHUNK (NROWS / RPC)   // 256 blocks

// ---------------------------------------------------------------------------
// Stage 1: per-(row-chunk) partial sums of the 5 stats for ALL columns.
// One 1024-thread block spans the full 4096-col row (thread t owns cols
// 4t..4t+3, float4 = 16 B/lane). Each block streams 64 contiguous rows
// (2x 4 MB). grid = 256 blocks = 1 block/CU = 16 waves/CU (round 1 showed
// even 8 waves/CU saturates the read path; stage-1 BW is config-invariant
// at ~4.3 TB/s across rounds 1-4).
// partial layout: [gy][5][NCOLS] floats -> 20 MB total (halves stage-2 read).
// ---------------------------------------------------------------------------
__global__ __launch_bounds__(1024, 8) void stats_partial_kernel(
    const float* __restrict__ preds,
    const float* __restrict__ targets,
    float* __restrict__ partial)
{
    const int col = threadIdx.x * 4;
    const size_t r0 = (size_t)blockIdx.x * RPC;

    const float* __restrict__ pp = preds   + r0 * NCOLS + col;
    const float* __restrict__ tp = targets + r0 * NCOLS + col;

    float4 sp  = {0.f, 0.f, 0.f, 0.f};
    float4 st  = {0.f, 0.f, 0.f, 0.f};
    float4 spp = {0.f, 0.f, 0.f, 0.f};
    float4 stt = {0.f, 0.f, 0.f, 0.f};
    float4 spt = {0.f, 0.f, 0.f, 0.f};

    #pragma unroll 4
    for (int r = 0; r < RPC; ++r) {
        float4 p = *(const float4*)pp;
        float4 t = *(const float4*)tp;
        sp.x  += p.x;        sp.y  += p.y;        sp.z  += p.z;        sp.w  += p.w;
        st.x  += t.x;        st.y  += t.y;        st.z  += t.z;        st.w  += t.w;
        spp.x += p.x * p.x;  spp.y += p.y * p.y;  spp.z += p.z * p.z;  spp.w += p.w * p.w;
        stt.x += t.x * t.x;  stt.y += t.y * t.y;  stt.z += t.z * t.z;  stt.w += t.w * t.w;
        spt.x += p.x * t.x;  spt.y += p.y * t.y;  spt.z += p.z * t.z;  spt.w += p.w * t.w;
        pp += NCOLS;
        tp += NCOLS;
    }

    float* base = partial + ((size_t)blockIdx.x * 5) * NCOLS + col;
    *(float4*)(base + 0 * NCOLS) = sp;
    *(float4*)(base + 1 * NCOLS) = st;
    *(float4*)(base + 2 * NCOLS) = spp;
    *(float4*)(base + 3 * NCOLS) = stt;
    *(float4*)(base + 4 * NCOLS) = spt;
}

// ---------------------------------------------------------------------------
// Stage 2 (final): reduce partials over chunks, per-column pcc/cos, block
// reduction, one atomicAdd per block into d_out (init'd to 0 by memset).
// grid = NCOLS/16 = 256 blocks, 256 threads = 16 cols x 16 chunk-lanes.
// Each block adds (2/256 - blocksum/NCOLS); total = 2 - mean(pcc+cos).
// ---------------------------------------------------------------------------
__global__ __launch_bounds__(256) void reduce_cols_kernel(
    const float* __restrict__ partial,
    float* __restrict__ out)
{
    const int ci  = threadIdx.x & 15;   // column within block
    const int gi  = threadIdx.x >> 4;   // chunk-lane 0..15
    const int col = blockIdx.x * 16 + ci;

    float s[5] = {0.f, 0.f, 0.f, 0.f, 0.f};
    #pragma unroll
    for (int gy = gi; gy < NCHUNK; gy += 16) {
        const float* base = partial + ((size_t)gy * 5) * NCOLS + col;
        #pragma unroll
        for (int k = 0; k < 5; ++k) s[k] += base[k * NCOLS];
    }

    __shared__ float red[256][5];
    #pragma unroll
    for (int k = 0; k < 5; ++k) red[threadIdx.x][k] = s[k];
    __syncthreads();

    __shared__ float colval[16];
    if (threadIdx.x < 16) {
        float t[5] = {0.f, 0.f, 0.f, 0.f, 0.f};
        for (int g = 0; g < 16; ++g) {
            #pragma unroll
            for (int k = 0; k < 5; ++k) t[k] += red[threadIdx.x + 16 * g][k];
        }
        // t = {sum_p, sum_t, sum_pp, sum_tt, sum_pt}
        const float invN = 1.0f / (float)NROWS;
        float mu_p = t[0] * invN;
        float mu_t = t[1] * invN;
        float var_p = fmaxf(t[2] * invN - mu_p * mu_p, 0.f);
        float var_t = fmaxf(t[3] * invN - mu_t * mu_t, 0.f);
        float cov   = t[4] * invN - mu_p * mu_t;

        float denom = sqrtf(var_p * var_t);
        float pcc = (denom > 0.f) ? (cov / denom) : 0.f;  // NaN -> 0 semantics

        float np_ = fmaxf(sqrtf(t[2]), 1e-8f);
        float nt_ = fmaxf(sqrtf(t[3]), 1e-8f);
        float cs  = t[4] / (np_ * nt_);

        colval[threadIdx.x] = pcc + cs;
    }
    __syncthreads();

    if (threadIdx.x == 0) {
        float b = 0.f;
        #pragma unroll
        for (int i = 0; i < 16; ++i) b += colval[i];
        float contrib = 2.0f / 256.0f - b / (float)NCOLS;
        atomicAdd(out, contrib);
    }
}

extern "C" void kernel_launch(void* const* d_in, const int* in_sizes, int n_in,
                              void* d_out, int out_size, void* d_ws, size_t ws_size,
                              hipStream_t stream) {
    const float* preds   = (const float*)d_in[0];
    const float* targets = (const float*)d_in[1];
    float* out = (float*)d_out;
    float* partial = (float*)d_ws;   // NCHUNK*5*NCOLS*4 = 20 MB (ws ~1 GB)

    hipMemsetAsync(d_out, 0, sizeof(float), stream);

    stats_partial_kernel<<<NCHUNK, 1024, 0, stream>>>(preds, targets, partial);
    reduce_cols_kernel<<<NCOLS / 16, 256, 0, stream>>>(partial, out);
}